// Round 2
// baseline (1157.983 us; speedup 1.0000x reference)
//
#include <hip/hip_runtime.h>
#include <hip/hip_bf16.h>

#define BB 32
#define AA 128
#define DD 512
#define HH 8
#define DH 64

typedef __attribute__((ext_vector_type(8))) short short8;
typedef __attribute__((ext_vector_type(4))) float f32x4;

// fp32 -> bf16 with round-to-nearest-even (bit trick; no NaN inputs here)
__device__ __forceinline__ unsigned short f2bf(float f) {
  unsigned u = __builtin_bit_cast(unsigned, f);
  u += 0x7FFFu + ((u >> 16) & 1u);
  return (unsigned short)(u >> 16);
}

// ---------------------------------------------------------------------------
// Per-agent GEMM: Y[m, a, n] = sum_k X[m, a, k] * W[a*astride + k*512 + n]
// X layout: [(m*AA + a)*DD + k]   (m = batch row, a = agent)
// grid = AA*4 blocks (4 column tiles of 128), 256 threads (4 waves).
// Tile: M=32 x N=128, K-step 32, bf16 MFMA 16x16x32, fp32 accum.
// EPI=0: plain store to Y.  EPI=1: f = acc + bias[a,n]; H += silu(f).
// ---------------------------------------------------------------------------
template<int EPI>
__global__ __launch_bounds__(256) void gemm_pa(
    const float* __restrict__ X, const float* __restrict__ W, size_t astride,
    float* __restrict__ Y, const float* __restrict__ bias, float* __restrict__ H)
{
  __shared__ unsigned short a_sh[32 * 40];    // A tile [m][k], row stride 40 (pad)
  __shared__ unsigned short b_sh[128 * 40];   // B tile transposed [n][k], stride 40

  const int t  = threadIdx.x;
  const int a  = blockIdx.x >> 2;
  const int nt = blockIdx.x & 3;
  const int l  = t & 63;
  const int w  = t >> 6;
  const int rr = l & 15;
  const int kb = (l >> 4) * 8;      // k base within 32 for MFMA frags

  const float* Xa = X + (size_t)a * DD;
  const float* Wa = W + (size_t)a * astride + nt * 128;

  f32x4 acc[2][2];
  #pragma unroll
  for (int i = 0; i < 2; ++i)
    #pragma unroll
    for (int j = 0; j < 2; ++j) acc[i][j] = (f32x4){0.f, 0.f, 0.f, 0.f};

  const int am = t >> 3;            // A-stage: row 0..31
  const int ak = (t & 7) * 4;       // A-stage: k 0..28

  for (int k0 = 0; k0 < DD; k0 += 32) {
    // stage A: 32x32 fp32 -> bf16 (one float4 per thread)
    {
      float4 v = *reinterpret_cast<const float4*>(Xa + (size_t)am * (AA * DD) + k0 + ak);
      unsigned lo = (unsigned)f2bf(v.x) | ((unsigned)f2bf(v.y) << 16);
      unsigned hi = (unsigned)f2bf(v.z) | ((unsigned)f2bf(v.w) << 16);
      uint2 pk; pk.x = lo; pk.y = hi;
      *reinterpret_cast<uint2*>(&a_sh[am * 40 + ak]) = pk;
    }
    // stage B: 32(k) x 128(n) fp32, transposed into [n][k] bf16
    #pragma unroll
    for (int p = 0; p < 4; ++p) {
      int idx4 = p * 256 + t;
      int k = idx4 >> 5;
      int n = (idx4 & 31) * 4;
      float4 v = *reinterpret_cast<const float4*>(Wa + (size_t)(k0 + k) * DD + n);
      b_sh[(n + 0) * 40 + k] = f2bf(v.x);
      b_sh[(n + 1) * 40 + k] = f2bf(v.y);
      b_sh[(n + 2) * 40 + k] = f2bf(v.z);
      b_sh[(n + 3) * 40 + k] = f2bf(v.w);
    }
    __syncthreads();
    // MFMA frags: A row = l&15 (+m0), k = (l>>4)*8 + e ; B col = l&15 (+n0), same k
    short8 a0 = *reinterpret_cast<const short8*>(&a_sh[(rr)      * 40 + kb]);
    short8 a1 = *reinterpret_cast<const short8*>(&a_sh[(16 + rr) * 40 + kb]);
    short8 b0 = *reinterpret_cast<const short8*>(&b_sh[(w * 32 + rr)      * 40 + kb]);
    short8 b1 = *reinterpret_cast<const short8*>(&b_sh[(w * 32 + 16 + rr) * 40 + kb]);
    acc[0][0] = __builtin_amdgcn_mfma_f32_16x16x32_bf16(a0, b0, acc[0][0], 0, 0, 0);
    acc[0][1] = __builtin_amdgcn_mfma_f32_16x16x32_bf16(a0, b1, acc[0][1], 0, 0, 0);
    acc[1][0] = __builtin_amdgcn_mfma_f32_16x16x32_bf16(a1, b0, acc[1][0], 0, 0, 0);
    acc[1][1] = __builtin_amdgcn_mfma_f32_16x16x32_bf16(a1, b1, acc[1][1], 0, 0, 0);
    __syncthreads();
  }

  // epilogue: D layout col = lane&15, row = (lane>>4)*4 + reg  [m89/m91]
  #pragma unroll
  for (int mi = 0; mi < 2; ++mi) {
    #pragma unroll
    for (int ni = 0; ni < 2; ++ni) {
      int ncol = nt * 128 + w * 32 + ni * 16 + rr;
      #pragma unroll
      for (int r = 0; r < 4; ++r) {
        int m = mi * 16 + (l >> 4) * 4 + r;
        size_t idx = ((size_t)m * AA + a) * DD + ncol;
        float val = acc[mi][ni][r];
        if (EPI == 0) {
          Y[idx] = val;
        } else {
          float f = val + bias[(size_t)a * DD + ncol];
          float s = f / (1.f + __expf(-f));   // silu
          H[idx] += s;
        }
      }
    }
  }
}

// ---------------------------------------------------------------------------
// LayerNorm over last dim (512). One 64-lane wave per row, 4 rows per block.
// ---------------------------------------------------------------------------
__global__ __launch_bounds__(256) void ln_kernel(
    const float* __restrict__ X, float* __restrict__ Y,
    const float* __restrict__ g, const float* __restrict__ be)
{
  int row = blockIdx.x * 4 + (threadIdx.x >> 6);
  int l = threadIdx.x & 63;
  const float* xr = X + (size_t)row * DD + l * 8;
  float4 v0 = *reinterpret_cast<const float4*>(xr);
  float4 v1 = *reinterpret_cast<const float4*>(xr + 4);

  float s = v0.x + v0.y + v0.z + v0.w + v1.x + v1.y + v1.z + v1.w;
  #pragma unroll
  for (int off = 32; off > 0; off >>= 1) s += __shfl_xor(s, off);
  float mu = s * (1.f / DD);

  float q = 0.f, d;
  d = v0.x - mu; q += d * d;  d = v0.y - mu; q += d * d;
  d = v0.z - mu; q += d * d;  d = v0.w - mu; q += d * d;
  d = v1.x - mu; q += d * d;  d = v1.y - mu; q += d * d;
  d = v1.z - mu; q += d * d;  d = v1.w - mu; q += d * d;
  #pragma unroll
  for (int off = 32; off > 0; off >>= 1) q += __shfl_xor(q, off);
  float inv = rsqrtf(q * (1.f / DD) + 1e-5f);

  float4 g0 = *reinterpret_cast<const float4*>(g + l * 8);
  float4 g1 = *reinterpret_cast<const float4*>(g + l * 8 + 4);
  float4 b0 = *reinterpret_cast<const float4*>(be + l * 8);
  float4 b1 = *reinterpret_cast<const float4*>(be + l * 8 + 4);
  float4 o0, o1;
  o0.x = (v0.x - mu) * inv * g0.x + b0.x;  o0.y = (v0.y - mu) * inv * g0.y + b0.y;
  o0.z = (v0.z - mu) * inv * g0.z + b0.z;  o0.w = (v0.w - mu) * inv * g0.w + b0.w;
  o1.x = (v1.x - mu) * inv * g1.x + b1.x;  o1.y = (v1.y - mu) * inv * g1.y + b1.y;
  o1.z = (v1.z - mu) * inv * g1.z + b1.z;  o1.w = (v1.w - mu) * inv * g1.w + b1.w;
  float* yr = Y + (size_t)row * DD + l * 8;
  *reinterpret_cast<float4*>(yr) = o0;
  *reinterpret_cast<float4*>(yr + 4) = o1;
}

// ---------------------------------------------------------------------------
// Attention per (b, head): scores = QK^T/8 + connect; softmax; O = attn @ V.
// Block = (b*8 + head), 256 threads. fp32 throughout.
// LDS: sA = K padded [128][65] (reused for V [128][64]); sB = Q [128][64]
// (reused for attn probs [128][130]).
// ---------------------------------------------------------------------------
__global__ __launch_bounds__(256) void attn_kernel(
    const float* __restrict__ Q, const float* __restrict__ K,
    const float* __restrict__ V, const float* __restrict__ C,
    float* __restrict__ O)
{
  __shared__ float sA[128 * 65];
  __shared__ float sB[128 * 130];
  const int t = threadIdx.x;
  const int b = blockIdx.x >> 3;
  const int hd = blockIdx.x & 7;
  const int l = t & 63;
  const int w = t >> 6;
  const size_t base = ((size_t)b * AA) * DD + hd * DH;   // + a*DD + d

  // stage Q (stride 64) and K (padded stride 65, scalar writes)
  #pragma unroll
  for (int p = 0; p < 8; ++p) {
    int idx = (p * 256 + t) * 4;
    int e = idx >> 6;
    int dd = idx & 63;
    float4 qv = *reinterpret_cast<const float4*>(Q + base + (size_t)e * DD + dd);
    *reinterpret_cast<float4*>(&sB[e * 64 + dd]) = qv;
    float4 kv = *reinterpret_cast<const float4*>(K + base + (size_t)e * DD + dd);
    sA[e * 65 + dd + 0] = kv.x;  sA[e * 65 + dd + 1] = kv.y;
    sA[e * 65 + dd + 2] = kv.z;  sA[e * 65 + dd + 3] = kv.w;
  }
  __syncthreads();

  // scores: wave w owns rows a = w*32 + i; lane l owns cols e = l and l+64
  float p0[32], p1[32];
  #pragma unroll
  for (int i = 0; i < 32; ++i) { p0[i] = 0.f; p1[i] = 0.f; }
  for (int dd = 0; dd < 64; ++dd) {
    float k0 = sA[l * 65 + dd];            // per-lane, bank-spread by pad
    float k1 = sA[(64 + l) * 65 + dd];
    #pragma unroll
    for (int i = 0; i < 32; ++i) {
      float qv = sB[(w * 32 + i) * 64 + dd];   // wave-uniform -> broadcast
      p0[i] += qv * k0;
      p1[i] += qv * k1;
    }
  }

  // softmax over e (64 lanes x 2 halves) per row
  const float scale = 0.125f;   // Dh^-0.5
  #pragma unroll
  for (int i = 0; i < 32; ++i) {
    int arow = w * 32 + i;
    float c0 = C[arow * 128 + l];
    float c1 = C[arow * 128 + 64 + l];
    float s0 = p0[i] * scale + c0;
    float s1 = p1[i] * scale + c1;
    float m = fmaxf(s0, s1);
    #pragma unroll
    for (int off = 32; off > 0; off >>= 1) m = fmaxf(m, __shfl_xor(m, off));
    float e0 = __expf(s0 - m);
    float e1 = __expf(s1 - m);
    float sum = e0 + e1;
    #pragma unroll
    for (int off = 32; off > 0; off >>= 1) sum += __shfl_xor(sum, off);
    float rinv = 1.f / sum;
    p0[i] = e0 * rinv;
    p1[i] = e1 * rinv;
  }
  __syncthreads();   // everyone done reading Q/K; safe to overwrite

  // write attn probs (stride 130) and stage V (stride 64, over old K)
  #pragma unroll
  for (int i = 0; i < 32; ++i) {
    int arow = w * 32 + i;
    sB[arow * 130 + l]      = p0[i];
    sB[arow * 130 + 64 + l] = p1[i];
  }
  #pragma unroll
  for (int p = 0; p < 8; ++p) {
    int idx = (p * 256 + t) * 4;
    int e = idx >> 6;
    int dd = idx & 63;
    float4 vv = *reinterpret_cast<const float4*>(V + base + (size_t)e * DD + dd);
    *reinterpret_cast<float4*>(&sA[e * 64 + dd]) = vv;
  }
  __syncthreads();

  // O = attn @ V : thread tile 4 rows x 8 cols
  const int ag = t >> 3;          // a = ag*4 + i
  const int dg = t & 7;           // d = dg*8 + j
  float o[4][8];
  #pragma unroll
  for (int i = 0; i < 4; ++i)
    #pragma unroll
    for (int j = 0; j < 8; ++j) o[i][j] = 0.f;
  for (int e = 0; e < 128; ++e) {
    float vv[8];
    #pragma unroll
    for (int j = 0; j < 8; ++j) vv[j] = sA[e * 64 + dg * 8 + j];
    #pragma unroll
    for (int i = 0; i < 4; ++i) {
      float at = sB[(ag * 4 + i) * 130 + e];
      #pragma unroll
      for (int j = 0; j < 8; ++j) o[i][j] += at * vv[j];
    }
  }
  #pragma unroll
  for (int i = 0; i < 4; ++i) {
    int arow = ag * 4 + i;
    #pragma unroll
    for (int j = 0; j < 8; ++j)
      O[base + (size_t)arow * DD + dg * 8 + j] = o[i][j];
  }
}

// ---------------------------------------------------------------------------
extern "C" void kernel_launch(void* const* d_in, const int* in_sizes, int n_in,
                              void* d_out, int out_size, void* d_ws, size_t ws_size,
                              hipStream_t stream) {
  const float* x     = (const float*)d_in[0];
  const float* W_emb = (const float*)d_in[1];
  const float* ln0g  = (const float*)d_in[2];
  const float* ln0b  = (const float*)d_in[3];
  const float* W_q   = (const float*)d_in[4];
  const float* W_k   = (const float*)d_in[5];
  const float* W_v   = (const float*)d_in[6];
  const float* W_fwd = (const float*)d_in[7];
  const float* b_fwd = (const float*)d_in[8];
  const float* ln1g  = (const float*)d_in[9];
  const float* ln1b  = (const float*)d_in[10];
  const float* conn  = (const float*)d_in[11];

  float* h  = (float*)d_out;                 // h lives in d_out the whole time
  float* ws = (float*)d_ws;
  const size_t NE = (size_t)BB * AA * DD;    // 2M floats
  float* xn = ws;            // also attn output (aliased after xn dead)
  float* qb = ws + NE;       // also LN(attn out) (aliased after q dead)
  float* kb = ws + 2 * NE;
  float* vb = ws + 3 * NE;   // total ws use: 32 MB

  dim3 blk(256);
  const size_t AS = (size_t)DD * DD;

  // embed: emb = x @ W_embed[a]  -> xn ; h = LN0(emb)
  gemm_pa<0><<<512, blk, 0, stream>>>(x, W_emb, AS, xn, nullptr, nullptr);
  ln_kernel<<<1024, blk, 0, stream>>>(xn, h, ln0g, ln0b);

  for (int s = 0; s < 3; ++s) {
    ln_kernel<<<1024, blk, 0, stream>>>(h, xn, ln1g, ln1b);
    gemm_pa<0><<<512, blk, 0, stream>>>(xn, W_q, AS, qb, nullptr, nullptr);
    gemm_pa<0><<<512, blk, 0, stream>>>(xn, W_k, AS, kb, nullptr, nullptr);
    gemm_pa<0><<<512, blk, 0, stream>>>(xn, W_v, 0, vb, nullptr, nullptr);
    attn_kernel<<<256, blk, 0, stream>>>(qb, kb, vb, conn, xn);
    ln_kernel<<<1024, blk, 0, stream>>>(xn, qb, ln1g, ln1b);
    gemm_pa<1><<<512, blk, 0, stream>>>(qb, W_fwd, AS, nullptr, b_fwd, h);
  }
}